// Round 1
// baseline (4614.070 us; speedup 1.0000x reference)
//
#include <hip/hip_runtime.h>

typedef unsigned short u16;
typedef unsigned int u32;
typedef __bf16 bfx8 __attribute__((ext_vector_type(8)));
typedef float f32x4 __attribute__((ext_vector_type(4)));

constexpr int BB = 64;     // batch
constexpr int TT = 64;     // time
constexpr int EE = 2048;   // x feature
constexpr int DD = 4096;   // deter
constexpr int GG = 8;      // groups
constexpr int H3 = 3 * DD;       // 12288
constexpr int CH = H3 / GG;      // 1536
constexpr float EPSf = 1e-4f;

static __device__ __forceinline__ u16 f2bf(float f) {
  u32 u = __builtin_bit_cast(u32, f);
  u32 r = (u + 0x7fffu + ((u >> 16) & 1u)) >> 16;
  return (u16)r;
}

// ---------------- prepass kernels ----------------

__global__ void __launch_bounds__(256) k_f2b(const float* __restrict__ in,
                                             u16* __restrict__ out, int n4) {
  int i = blockIdx.x * 256 + threadIdx.x;
  int stride = gridDim.x * 256;
  for (; i < n4; i += stride) {
    float4 v = ((const float4*)in)[i];
    uint2 o;
    o.x = (u32)f2bf(v.x) | ((u32)f2bf(v.y) << 16);
    o.y = (u32)f2bf(v.z) | ((u32)f2bf(v.w) << 16);
    ((uint2*)out)[i] = o;
  }
}

__global__ void __launch_bounds__(256) k_initdet(const float* __restrict__ d0,
                                                 float* __restrict__ dF,
                                                 u16* __restrict__ dB, int n4) {
  int i = blockIdx.x * 256 + threadIdx.x;
  if (i < n4) {
    float4 v = ((const float4*)d0)[i];
    ((float4*)dF)[i] = v;
    uint2 o;
    o.x = (u32)f2bf(v.x) | ((u32)f2bf(v.y) << 16);
    o.y = (u32)f2bf(v.z) | ((u32)f2bf(v.w) << 16);
    ((uint2*)dB)[i] = o;
  }
}

// in [R][C] f32 -> out [C][R] bf16  (batched over blockIdx.z)
__global__ void __launch_bounds__(256) k_transpose_f2b(const float* __restrict__ in,
                                                       u16* __restrict__ out,
                                                       int R, int C) {
  __shared__ float tile[32][33];
  size_t base = (size_t)blockIdx.z * R * C;
  in += base; out += base;
  int tx = threadIdx.x & 31, ty = threadIdx.x >> 5;
  int r0 = blockIdx.y * 32, c0 = blockIdx.x * 32;
#pragma unroll
  for (int i = 0; i < 4; i++) {
    int rr = ty * 4 + i;
    tile[rr][tx] = in[(size_t)(r0 + rr) * C + (c0 + tx)];
  }
  __syncthreads();
#pragma unroll
  for (int i = 0; i < 4; i++) {
    int cc = ty * 4 + i;
    out[(size_t)(c0 + cc) * R + (r0 + tx)] = f2bf(tile[tx][cc]);
  }
}

// ---------------- GEMM: A[m][k] (row-major, bf16) x B[n][k] (row-major, bf16) -> C f32 ----------------
// grid.z adds element offsets: A += z*aZ (k-offset), B += z*bZ, C += z*cZ, bias += z*biasZ

template<int BM, int BN, int WR, int WC>
__global__ void __launch_bounds__(256) k_gemm(
    const u16* __restrict__ A, int lda, int aZ,
    const u16* __restrict__ B, int ldb, int bZ,
    float* __restrict__ C, int ldc, long long cZ,
    const float* __restrict__ bias, int biasZ,
    int K) {
  constexpr int BK = 64, LS = BK + 8;  // +8 bf16 pad keeps 16B align, breaks bank conflicts
  constexpr int WTM = BM / WR, WTN = BN / WC, MF = WTM / 16, NF = WTN / 16;
  __shared__ u16 As[BM * LS];
  __shared__ u16 Bs[BN * LS];
  const int tid = threadIdx.x;
  const int z = blockIdx.z;
  A += (size_t)z * aZ;
  B += (size_t)z * bZ;
  C += (size_t)z * cZ;
  const int m0 = blockIdx.y * BM, n0 = blockIdx.x * BN;
  const int w = tid >> 6, lane = tid & 63;
  const int wr = w / WC, wc = w % WC;
  const int lr = lane & 15, lk = (lane >> 4) * 8;

  f32x4 acc[MF][NF] = {};

  for (int kt = 0; kt < K; kt += BK) {
#pragma unroll
    for (int c = tid; c < BM * 8; c += 256) {
      int row = c >> 3, cc = c & 7;
      uint4 v = *(const uint4*)(A + (size_t)(m0 + row) * lda + kt + cc * 8);
      *(uint4*)&As[row * LS + cc * 8] = v;
    }
#pragma unroll
    for (int c = tid; c < BN * 8; c += 256) {
      int row = c >> 3, cc = c & 7;
      uint4 v = *(const uint4*)(B + (size_t)(n0 + row) * ldb + kt + cc * 8);
      *(uint4*)&Bs[row * LS + cc * 8] = v;
    }
    __syncthreads();
#pragma unroll
    for (int kk = 0; kk < BK; kk += 32) {
      bfx8 av[MF], bv[NF];
#pragma unroll
      for (int mi = 0; mi < MF; mi++)
        av[mi] = *(const bfx8*)&As[(wr * WTM + mi * 16 + lr) * LS + kk + lk];
#pragma unroll
      for (int ni = 0; ni < NF; ni++)
        bv[ni] = *(const bfx8*)&Bs[(wc * WTN + ni * 16 + lr) * LS + kk + lk];
#pragma unroll
      for (int mi = 0; mi < MF; mi++)
#pragma unroll
        for (int ni = 0; ni < NF; ni++)
          acc[mi][ni] = __builtin_amdgcn_mfma_f32_16x16x32_bf16(av[mi], bv[ni], acc[mi][ni], 0, 0, 0);
    }
    __syncthreads();
  }

  // C/D layout: col = lane&15, row = (lane>>4)*4 + reg   [m89-verified]
  const int rq = (lane >> 4) * 4;
#pragma unroll
  for (int mi = 0; mi < MF; mi++) {
#pragma unroll
    for (int ni = 0; ni < NF; ni++) {
      int n = n0 + wc * WTN + ni * 16 + lr;
      float bias_v = bias ? bias[(size_t)z * biasZ + n] : 0.f;
#pragma unroll
      for (int r = 0; r < 4; r++) {
        int m = m0 + wr * WTM + mi * 16 + rq + r;
        C[(size_t)m * ldc + n] = acc[mi][ni][r] + bias_v;
      }
    }
  }
}

// ---------------- K2: reduce split-K partials + Xproj, row-RMS, silu -> y bf16 ----------------
__global__ void __launch_bounds__(256) k_rmsilu(const float* __restrict__ part,
                                                const float* __restrict__ xproj,
                                                const float* __restrict__ scale,
                                                u16* __restrict__ y, int t) {
  int b = blockIdx.x, tid = threadIdx.x;
  const float* xp = xproj + ((size_t)b * TT + t) * DD;
  const float* pb = part + (size_t)b * DD;
  float v[16];
  float ss = 0.f;
#pragma unroll
  for (int j = 0; j < 4; j++) {
    int n = tid * 16 + j * 4;
    float4 a = *(const float4*)(xp + n);
#pragma unroll
    for (int kc = 0; kc < 4; kc++) {
      float4 p = *(const float4*)(pb + (size_t)kc * BB * DD + n);
      a.x += p.x; a.y += p.y; a.z += p.z; a.w += p.w;
    }
    v[j * 4] = a.x; v[j * 4 + 1] = a.y; v[j * 4 + 2] = a.z; v[j * 4 + 3] = a.w;
    ss += a.x * a.x + a.y * a.y + a.z * a.z + a.w * a.w;
  }
#pragma unroll
  for (int o = 32; o > 0; o >>= 1) ss += __shfl_down(ss, o);
  __shared__ float wsum[4];
  if ((tid & 63) == 0) wsum[tid >> 6] = ss;
  __syncthreads();
  float tot = wsum[0] + wsum[1] + wsum[2] + wsum[3];
  float r = rsqrtf(tot / (float)DD + EPSf);
#pragma unroll
  for (int j = 0; j < 16; j++) {
    int n = tid * 16 + j;
    float yv = v[j] * r * scale[n];
    yv = yv / (1.f + __expf(-yv));  // silu
    y[(size_t)b * DD + n] = f2bf(yv);
  }
}

// ---------------- K4: per-block RMS + gates + deter update + output ----------------
__global__ void __launch_bounds__(256) k_gates(const float* __restrict__ zb,
                                               const float* __restrict__ sblk,
                                               float* __restrict__ dF,
                                               u16* __restrict__ dB,
                                               float* __restrict__ out, int t) {
  int b = blockIdx.x, tid = threadIdx.x;
  const float* zr = zb + (size_t)b * H3;
  float ss = 0.f;
#pragma unroll
  for (int j = 0; j < 12; j++) {  // 48 elems/thread, each span inside one 1536-chunk
    float4 a = *(const float4*)(zr + tid * 48 + j * 4);
    ss += a.x * a.x + a.y * a.y + a.z * a.z + a.w * a.w;
  }
#pragma unroll
  for (int o = 16; o > 0; o >>= 1) ss += __shfl_down(ss, o);  // sums 32-lane groups
  __shared__ float rs[8];
  if ((tid & 31) == 0) rs[tid >> 5] = ss;
  __syncthreads();
  if (tid < 8) rs[tid] = rsqrtf(rs[tid] / (float)CH + EPSf);
  __syncthreads();
#pragma unroll
  for (int j = 0; j < 16; j++) {
    int d = tid * 16 + j;
    float z0 = zr[d] * rs[d / CH] * sblk[d];
    float z1 = zr[DD + d] * rs[(DD + d) / CH] * sblk[DD + d];
    float z2 = zr[2 * DD + d] * rs[(2 * DD + d) / CH] * sblk[2 * DD + d];
    float reset = 1.f / (1.f + __expf(-z0));
    float cand = tanhf(reset * z1);
    float upd = 1.f / (1.f + __expf(-(z2 - 1.f)));
    float dold = dF[(size_t)b * DD + d];
    float dn = upd * cand + (1.f - upd) * dold;
    dF[(size_t)b * DD + d] = dn;
    dB[(size_t)b * DD + d] = f2bf(dn);
    out[((size_t)b * TT + t) * DD + d] = dn;
  }
}

// ---------------- host ----------------

extern "C" void kernel_launch(void* const* d_in, const int* in_sizes, int n_in,
                              void* d_out, int out_size, void* d_ws, size_t ws_size,
                              hipStream_t stream) {
  (void)in_sizes; (void)n_in; (void)out_size; (void)ws_size;
  const float* x         = (const float*)d_in[0];  // [B,T,E]
  const float* deter0    = (const float*)d_in[1];  // [B,D]
  const float* W_in      = (const float*)d_in[2];  // [D+E, D]
  const float* b_in      = (const float*)d_in[3];  // [D]
  const float* scale_in  = (const float*)d_in[4];  // [D]
  const float* W_blk     = (const float*)d_in[5];  // [G, D/G, 3D/G]
  const float* b_blk     = (const float*)d_in[6];  // [3D]
  const float* scale_blk = (const float*)d_in[7];  // [G, 3D/G]
  float* out = (float*)d_out;

  char* ws = (char*)d_ws;
  size_t off = 0;
  auto alloc = [&](size_t bytes) -> void* {
    void* p = ws + off;
    off += (bytes + 255) & ~(size_t)255;
    return p;
  };
  u16*   WT    = (u16*)alloc((size_t)DD * (DD + EE) * 2);  // [4096][6144]: WT[n][k] = W_in[k][n]
  u16*   WbT   = (u16*)alloc((size_t)GG * CH * (DD / GG) * 2);  // [g][1536][512]
  u16*   xbf   = (u16*)alloc((size_t)BB * TT * EE * 2);
  float* Xproj = (float*)alloc((size_t)BB * TT * DD * 4);
  float* part  = (float*)alloc((size_t)4 * BB * DD * 4);
  u16*   ybf   = (u16*)alloc((size_t)BB * DD * 2);
  float* zbuf  = (float*)alloc((size_t)BB * H3 * 4);
  float* dF    = (float*)alloc((size_t)BB * DD * 4);
  u16*   dB    = (u16*)alloc((size_t)BB * DD * 2);

  // prepass: convert & transpose
  k_f2b<<<dim3(2048), dim3(256), 0, stream>>>(x, xbf, BB * TT * EE / 4);
  k_transpose_f2b<<<dim3(DD / 32, (DD + EE) / 32, 1), dim3(256), 0, stream>>>(W_in, WT, DD + EE, DD);
  k_transpose_f2b<<<dim3(CH / 32, (DD / GG) / 32, GG), dim3(256), 0, stream>>>(W_blk, WbT, DD / GG, CH);
  k_initdet<<<dim3(BB * DD / 4 / 256), dim3(256), 0, stream>>>(deter0, dF, dB, BB * DD / 4);

  // P1: Xproj[b*T+t][:] = x[b][t][:] @ W2 + b_in   (M=4096, K=2048, N=4096)
  k_gemm<128, 128, 2, 2><<<dim3(DD / 128, BB * TT / 128, 1), dim3(256), 0, stream>>>(
      xbf, EE, 0,
      WT + DD, DD + EE, 0,   // W2T[n][k2] = WT[n][4096+k2], row stride 6144
      Xproj, DD, 0,
      b_in, 0,
      EE);

  for (int t = 0; t < TT; t++) {
    // K1: partials[kc] = deter_bf16 @ W1[kc-slice]  (M=64, N=4096, K=1024 per split)
    k_gemm<64, 64, 4, 1><<<dim3(DD / 64, 1, 4), dim3(256), 0, stream>>>(
        dB, DD, 1024,
        WT, DD + EE, 1024,
        part, DD, (long long)BB * DD,
        nullptr, 0,
        1024);
    // K2: y = silu(rms(sum(partials)+Xproj[:,t,:]) * scale_in)
    k_rmsilu<<<dim3(BB), dim3(256), 0, stream>>>(part, Xproj, scale_in, ybf, t);
    // K3: z[:, g*1536 + n] = y[:, g*512:+512] @ WblkT[g] + b_blk
    k_gemm<64, 64, 4, 1><<<dim3(CH / 64, 1, GG), dim3(256), 0, stream>>>(
        ybf, DD, DD / GG,
        WbT, DD / GG, CH * (DD / GG),
        zbuf, H3, (long long)CH,
        b_blk, CH,
        DD / GG);
    // K4: block rms + gates + deter update + out write
    k_gates<<<dim3(BB), dim3(256), 0, stream>>>(zbuf, scale_blk, dF, dB, out, t);
  }
}